// Round 19
// baseline (248.826 us; speedup 1.0000x reference)
//
#include <hip/hip_runtime.h>

// ---------------- problem constants ----------------
#define D_MODEL 1024
#define HID     2752
#define NEXP    8
#define NTOK    4096
#define ALPHA   0.05f

// prep kernel tile counts
#define TILES_PER_MAT 344          // UV: 8 d-tiles x 43 h-tiles ; WD: 43 h-tiles x 8 d-tiles
#define TILES_UV  (TILES_PER_MAT * 16)   // 5504
#define TILES_WD  (TILES_PER_MAT * 8)    // 2752
#define RTR_BLKS  1024

// LDS tile strides (u16 elements, odd-word to spread banks)
#define TSU 66    // UV tile [128][66]
#define TSW 130   // WD tile [64][130]

typedef __bf16 bf16_t;
typedef bf16_t bf16x8 __attribute__((ext_vector_type(8)));
typedef float  f32x4  __attribute__((ext_vector_type(4)));
typedef float  vf4    __attribute__((ext_vector_type(4)));

// counted-wait primitives (T3/T4)
#define VM_WAIT4  asm volatile("s_waitcnt vmcnt(4)" ::: "memory")
#define VM_WAIT6  asm volatile("s_waitcnt vmcnt(6)" ::: "memory")
#define VM_WAIT0  asm volatile("s_waitcnt vmcnt(0)" ::: "memory")
#define LGKM0     asm volatile("s_waitcnt lgkmcnt(0)" ::: "memory")
#define SBAR      __builtin_amdgcn_s_barrier()
#define SCHED0    __builtin_amdgcn_sched_barrier(0)

__device__ inline unsigned short f2bf(float f) {
    unsigned int u = __float_as_uint(f);
    u += 0x7fffu + ((u >> 16) & 1u);   // round-to-nearest-even
    return (unsigned short)(u >> 16);
}

__device__ inline bf16x8 ldsFrag(const unsigned short* p) {
    union { uint4 u; bf16x8 b; } t;
    t.u = *(const uint4*)p;
    return t.b;
}

__device__ inline void gload_lds16(const void* g, void* l) {
    __builtin_amdgcn_global_load_lds((const __attribute__((address_space(1))) void*)g,
                                     (__attribute__((address_space(3))) void*)l, 16, 0, 0);
}

// ---------------- prep: weight transposes + router, one dispatch ----------------
// Round-18 proven body (2-tile pipeline, NT loads).
struct TileP {
    const float* src;
    unsigned short* dst;
    int r0, c0;
    bool uv;
};

__device__ inline TileP tileParams(int tt, const float* Wu, const float* Wv, const float* Wd,
                                   unsigned short* WuT, unsigned short* WvT, unsigned short* WdT) {
    TileP p;
    const int z  = tt / TILES_PER_MAT;
    const int rm = tt - z * TILES_PER_MAT;
    const int bx = rm % 43;
    const int by = rm / 43;
    if (z < 16) {
        const int e = z & 7;
        p.src = ((z < 8) ? Wu : Wv) + (size_t)e * D_MODEL * HID;
        p.dst = ((z < 8) ? WuT : WvT) + (size_t)e * D_MODEL * HID;
        p.r0 = by * 128; p.c0 = bx * 64; p.uv = true;
    } else {
        const int e = z - 16;
        p.src = Wd + (size_t)e * HID * D_MODEL;
        p.dst = WdT + (size_t)e * HID * D_MODEL;
        p.r0 = bx * 64; p.c0 = by * 128; p.uv = false;
    }
    return p;
}

__device__ inline void issueLoads(const TileP& p, int tid, vf4* v) {
    if (p.uv) {
#pragma unroll
        for (int j = 0; j < 8; ++j) {
            int f = j * 256 + tid;
            int row = f >> 4, c4 = (f & 15) * 4;
            v[j] = __builtin_nontemporal_load(
                (const vf4*)(p.src + (size_t)(p.r0 + row) * HID + p.c0 + c4));
        }
    } else {
#pragma unroll
        for (int j = 0; j < 8; ++j) {
            int f = j * 256 + tid;
            int row = f >> 5, c4 = (f & 31) * 4;
            v[j] = __builtin_nontemporal_load(
                (const vf4*)(p.src + (size_t)(p.r0 + row) * D_MODEL + p.c0 + c4));
        }
    }
}

__device__ inline void convertWrite(const TileP& p, int tid, const vf4* v, unsigned short* tile) {
    if (p.uv) {
#pragma unroll
        for (int j = 0; j < 8; ++j) {
            int f = j * 256 + tid;
            int row = f >> 4, c4 = (f & 15) * 4;
            unsigned int p0 = (unsigned)f2bf(v[j].x) | ((unsigned)f2bf(v[j].y) << 16);
            unsigned int p1 = (unsigned)f2bf(v[j].z) | ((unsigned)f2bf(v[j].w) << 16);
            unsigned int* tp = (unsigned int*)&tile[row * TSU + c4];
            tp[0] = p0; tp[1] = p1;
        }
    } else {
#pragma unroll
        for (int j = 0; j < 8; ++j) {
            int f = j * 256 + tid;
            int row = f >> 5, c4 = (f & 31) * 4;
            unsigned int p0 = (unsigned)f2bf(v[j].x) | ((unsigned)f2bf(v[j].y) << 16);
            unsigned int p1 = (unsigned)f2bf(v[j].z) | ((unsigned)f2bf(v[j].w) << 16);
            unsigned int* tp = (unsigned int*)&tile[row * TSW + c4];
            tp[0] = p0; tp[1] = p1;
        }
    }
}

__device__ inline void phase2(const TileP& p, int tid, const unsigned short* tile) {
    if (p.uv) {
#pragma unroll
        for (int j = 0; j < 4; ++j) {
            int f = j * 256 + tid;
            int oc = f >> 4, kc = f & 15;
            unsigned int w[4];
#pragma unroll
            for (int q = 0; q < 4; ++q) {
                unsigned int lo = tile[(kc * 8 + 2 * q)     * TSU + oc];
                unsigned int hi = tile[(kc * 8 + 2 * q + 1) * TSU + oc];
                w[q] = lo | (hi << 16);
            }
            uint4 out; out.x = w[0]; out.y = w[1]; out.z = w[2]; out.w = w[3];
            *(uint4*)(p.dst + (size_t)(p.c0 + oc) * D_MODEL + p.r0 + kc * 8) = out;
        }
    } else {
#pragma unroll
        for (int j = 0; j < 4; ++j) {
            int f = j * 256 + tid;
            int oc = f >> 3, kc = f & 7;
            unsigned int w[4];
#pragma unroll
            for (int q = 0; q < 4; ++q) {
                unsigned int lo = tile[(kc * 8 + 2 * q)     * TSW + oc];
                unsigned int hi = tile[(kc * 8 + 2 * q + 1) * TSW + oc];
                w[q] = lo | (hi << 16);
            }
            uint4 out; out.x = w[0]; out.y = w[1]; out.z = w[2]; out.w = w[3];
            *(uint4*)(p.dst + (size_t)(p.c0 + oc) * HID + p.r0 + kc * 8) = out;
        }
    }
}

__global__ __launch_bounds__(256) void prep_kernel(
    const float* __restrict__ x, const float* __restrict__ Wg, const float* __restrict__ bg,
    const float* __restrict__ Wu, const float* __restrict__ Wv, const float* __restrict__ Wd,
    unsigned short* __restrict__ WuT, unsigned short* __restrict__ WvT,
    unsigned short* __restrict__ WdT,
    int* __restrict__ eidx, float* __restrict__ gate_p,
    int* __restrict__ counts, float* __restrict__ ce_sum,
    unsigned short* __restrict__ xbf, int nPairs) {

    __shared__ __align__(16) unsigned short tile[128 * TSU];   // 16896 B (>= 64*TSW)
    const int id = blockIdx.x;
    const int tid = threadIdx.x;

    if (id < nPairs) {
        TileP p0 = tileParams(2 * id,     Wu, Wv, Wd, WuT, WvT, WdT);
        TileP p1 = tileParams(2 * id + 1, Wu, Wv, Wd, WuT, WvT, WdT);
        vf4 v[8];

        issueLoads(p0, tid, v);
        convertWrite(p0, tid, v, tile);
        __syncthreads();
        issueLoads(p1, tid, v);            // T1 loads fly under T0 phase-2
        SCHED0;
        phase2(p0, tid, tile);
        __syncthreads();
        convertWrite(p1, tid, v, tile);
        __syncthreads();
        phase2(p1, tid, tile);
        return;
    }

    // ---- router role ----
    float* ceS = (float*)tile;
    int*   cntS = (int*)tile + 8;
    if (tid < 8) { ceS[tid] = 0.f; cntS[tid] = 0; }
    __syncthreads();

    const int rid = id - nPairs;
    const int wid = tid >> 6, lane = tid & 63;
    const int t = rid * 4 + wid;
    const float* xr = x + (size_t)t * D_MODEL;
    unsigned short* xbr = xbf + (size_t)t * D_MODEL;

    float acc[8];
#pragma unroll
    for (int e = 0; e < 8; ++e) acc[e] = 0.f;

#pragma unroll
    for (int c = 0; c < 4; ++c) {
        int i0 = c * 256 + lane * 4;
        float4 xv = *(const float4*)(xr + i0);
        uint2 pk;
        pk.x = (unsigned)f2bf(xv.x) | ((unsigned)f2bf(xv.y) << 16);
        pk.y = (unsigned)f2bf(xv.z) | ((unsigned)f2bf(xv.w) << 16);
        *(uint2*)(xbr + i0) = pk;
#pragma unroll
        for (int j = 0; j < 4; ++j) {
            const float* wr = Wg + (size_t)(i0 + j) * 8;
            float4 lo = *(const float4*)(wr);
            float4 hi = *(const float4*)(wr + 4);
            float xs = (&xv.x)[j];
            acc[0] += xs * lo.x; acc[1] += xs * lo.y;
            acc[2] += xs * lo.z; acc[3] += xs * lo.w;
            acc[4] += xs * hi.x; acc[5] += xs * hi.y;
            acc[6] += xs * hi.z; acc[7] += xs * hi.w;
        }
    }
#pragma unroll
    for (int e = 0; e < 8; ++e) {
#pragma unroll
        for (int off = 32; off > 0; off >>= 1)
            acc[e] += __shfl_xor(acc[e], off, 64);
    }

    if (lane == 0) {
        float lg[8];
#pragma unroll
        for (int e = 0; e < 8; ++e) lg[e] = acc[e] + bg[e];
        float mx = lg[0]; int am = 0;
#pragma unroll
        for (int e = 1; e < 8; ++e) { if (lg[e] > mx) { mx = lg[e]; am = e; } }
        float ex[8], s = 0.f;
#pragma unroll
        for (int e = 0; e < 8; ++e) { ex[e] = __expf(lg[e] - mx); s += ex[e]; }
        float inv = 1.f / s;
#pragma unroll
        for (int e = 0; e < 8; ++e) atomicAdd(&ceS[e], ex[e] * inv);
        atomicAdd(&cntS[am], 1);
        eidx[t] = am;
        gate_p[t] = ex[am] * inv;
    }
    __syncthreads();
    if (tid < 8) atomicAdd(&ce_sum[tid], ceS[tid]);
    if (tid >= 8 && tid < 16) atomicAdd(&counts[tid - 8], cntS[tid - 8]);
}

// standalone Wd transpose (fallback when WdT must alias WuT; runs after gemm1)
__global__ __launch_bounds__(256) void transpose_kernel(const float* __restrict__ in,
                                                        unsigned short* __restrict__ out,
                                                        int R, int C) {
    __shared__ float tile[64 * 65];
    const int e = blockIdx.z;
    const float* src = in + (size_t)e * R * C;
    unsigned short* dst = out + (size_t)e * R * C;
    const int c0 = blockIdx.x * 64, r0 = blockIdx.y * 64;
    const int tid = threadIdx.x;
#pragma unroll
    for (int j = 0; j < 4; ++j) {
        int f = j * 256 + tid;
        int row = f >> 4, c4 = f & 15;
        float4 v = *(const float4*)(src + (size_t)(r0 + row) * C + c0 + c4 * 4);
        float* t = &tile[row * 65 + c4 * 4];
        t[0] = v.x; t[1] = v.y; t[2] = v.z; t[3] = v.w;
    }
    __syncthreads();
#pragma unroll
    for (int j = 0; j < 2; ++j) {
        int f = j * 256 + tid;
        int orow = f >> 3, kc = f & 7;
        unsigned short pk[8];
#pragma unroll
        for (int q = 0; q < 8; ++q) pk[q] = f2bf(tile[(kc * 8 + q) * 65 + orow]);
        *(uint4*)(dst + (size_t)(c0 + orow) * R + r0 + kc * 8) = *(uint4*)pk;
    }
}

// ---------------- scatter (+ folded offsets/aux) ----------------
__global__ void scatter_kernel(const int* __restrict__ eidx, const int* __restrict__ counts,
                               const float* __restrict__ ce_sum,
                               int* __restrict__ offs, float* __restrict__ aux_out,
                               int* __restrict__ fill, int* __restrict__ toks) {
    __shared__ int offS[8];
    const int tid = threadIdx.x;
    if (tid == 0) {
        int off = 0; float aux = 0.f;
#pragma unroll
        for (int e = 0; e < 8; ++e) {
            offS[e] = off;
            if (blockIdx.x == 0) offs[e] = off;
            off += counts[e];
            aux += ((float)counts[e] / (float)NTOK) * (ce_sum[e] / (float)NTOK);
        }
        if (blockIdx.x == 0) aux_out[0] = ALPHA * (float)NEXP * aux;
    }
    __syncthreads();
    int t = blockIdx.x * 256 + tid;
    int e = eidx[t];
    int pos = atomicAdd(&fill[e], 1);
    toks[offS[e] + pos] = t;
}

// ======================= GEMM1 =======================
// Round-19: 128m x 64n, BK=32, 4 waves, static ping-pong dbuf (32KB LDS ->
// 4-5 blocks/CU, 2-2.5x TLP vs BK=64's 64KB/2-blocks), counted vmcnt(4).
// Same barrier/vmcnt discipline as proven round-13 template.

#define G1_STAGE(AS, BUS, BVS)                                            \
    {                                                                     \
        _Pragma("unroll")                                                 \
        for (int i = 0; i < 2; ++i) { gload_lds16(aS[i], &AS[aOff[i]]); aS[i] += 32; } \
        gload_lds16(buS, &BUS[bOff]); buS += 32;                          \
        gload_lds16(bvS, &BVS[bOff]); bvS += 32;                          \
    }

#define G1_COMPUTE(AS, BUS, BVS)                                          \
    {                                                                     \
        bf16x8 af[4], bu[2], bv[2];                                       \
        _Pragma("unroll")                                                 \
        for (int m = 0; m < 4; ++m) {                                     \
            int r = rbase + m * 16 + lrow;                                \
            af[m] = ldsFrag(&AS[r * 32 + ((lchunk ^ (r & 3)) * 8)]);      \
        }                                                                 \
        _Pragma("unroll")                                                 \
        for (int n = 0; n < 2; ++n) {                                     \
            int rn = cbase + n * 16 + lrow;                               \
            int off = rn * 32 + ((lchunk ^ (rn & 3)) * 8);                \
            bu[n] = ldsFrag(&BUS[off]);                                   \
            bv[n] = ldsFrag(&BVS[off]);                                   \
        }                                                                 \
        __builtin_amdgcn_s_setprio(1);                                    \
        _Pragma("unroll")                                                 \
        for (int m = 0; m < 4; ++m)                                       \
            _Pragma("unroll")                                             \
            for (int n = 0; n < 2; ++n) {                                 \
                accU[m][n] = __builtin_amdgcn_mfma_f32_16x16x32_bf16(af[m], bu[n], accU[m][n], 0, 0, 0); \
                accV[m][n] = __builtin_amdgcn_mfma_f32_16x16x32_bf16(af[m], bv[n], accV[m][n], 0, 0, 0); \
            }                                                             \
        __builtin_amdgcn_s_setprio(0);                                    \
    }

__global__ __launch_bounds__(256, 2) void gemm1_kernel(
    const unsigned short* __restrict__ WuT, const unsigned short* __restrict__ WvT,
    const unsigned short* __restrict__ xbf,
    const int* __restrict__ toks, const int* __restrict__ counts, const int* __restrict__ offs,
    unsigned short* __restrict__ hbuf) {
    const int e  = blockIdx.z;
    const int mt = blockIdx.y;
    const int nt = blockIdx.x;           // 0..42
    const int Ne = counts[e];
    if (mt * 128 >= Ne) return;
    const int slot0 = offs[e] + mt * 128;
    const int rowsV = min(128, Ne - mt * 128);
    const int ncol0 = nt * 64;

    __shared__ unsigned short As0[128 * 32];   // 8 KB
    __shared__ unsigned short As1[128 * 32];
    __shared__ unsigned short Bus0[64 * 32];   // 4 KB
    __shared__ unsigned short Bus1[64 * 32];
    __shared__ unsigned short Bvs0[64 * 32];
    __shared__ unsigned short Bvs1[64 * 32];   // total 32 KB

    const int tid = threadIdx.x;

    // A: 128 rows x 4 chunks of 8 = 512 chunks -> 2/thread
    const unsigned short* aS[2];
    int aOff[2];
#pragma unroll
    for (int i = 0; i < 2; ++i) {
        int c = i * 256 + tid;
        int r = c >> 2, ch = c & 3;
        int srcOff = (ch ^ (r & 3)) * 8;
        int ar = min(r, rowsV - 1);
        int tok = toks[slot0 + ar];
        aS[i] = xbf + (size_t)tok * D_MODEL + srcOff;
        aOff[i] = c * 8;
    }
    // B: 64 rows x 4 chunks = 256 chunks -> 1/thread each
    const unsigned short *buS, *bvS;
    int bOff;
    {
        int c = tid;
        int r = c >> 2, ch = c & 3;
        int srcOff = (ch ^ (r & 3)) * 8;
        int bn = ncol0 + r;
        buS = WuT + ((size_t)e * HID + bn) * D_MODEL + srcOff;
        bvS = WvT + ((size_t)e * HID + bn) * D_MODEL + srcOff;
        bOff = c * 8;
    }

    f32x4 accU[4][2], accV[4][2];
#pragma unroll
    for (int m = 0; m < 4; ++m)
#pragma unroll
        for (int n = 0; n < 2; ++n) {
            accU[m][n] = (f32x4){0.f, 0.f, 0.f, 0.f};
            accV[m][n] = (f32x4){0.f, 0.f, 0.f, 0.f};
        }

    const int lane = tid & 63;
    const int w = tid >> 6;
    const int rbase = (w >> 1) * 64;
    const int cbase = (w & 1) * 32;
    const int lrow = lane & 15;
    const int lchunk = lane >> 4;

    // prologue: k=0 -> buf0 (4 VMEM outstanding)
    G1_STAGE(As0, Bus0, Bvs0);

    // 32 K-steps = 15 ping-pong pairs + tail pair
#pragma unroll 1
    for (int k2 = 0; k2 < 15; ++k2) {
        G1_STAGE(As1, Bus1, Bvs1);               // k = 2k2+1
        VM_WAIT4; SBAR; SCHED0;
        G1_COMPUTE(As0, Bus0, Bvs0);             // k = 2k2
        SCHED0; LGKM0; SBAR;
        G1_STAGE(As0, Bus0, Bvs0);               // k = 2k2+2
        VM_WAIT4; SBAR; SCHED0;
        G1_COMPUTE(As1, Bus1, Bvs1);             // k = 2k2+1
        SCHED0; LGKM0; SBAR;
    }
    G1_STAGE(As1, Bus1, Bvs1);                   // k = 31
    VM_WAIT4; SBAR; SCHED0;
    G1_COMPUTE(As0, Bus0, Bvs0);                 // k = 30
    SCHED0; LGKM0; SBAR;
    VM_WAIT0; SBAR; SCHED0;
    G1_COMPUTE(As1, Bus1, Bvs1);                 // k = 31

    // epilogue: h = silu(u) * v (bf16); HID = 43*64 so no column guard
#pragma unroll
    for (int m = 0; m < 4; ++m) {
#pragma unroll
        for (int i = 0; i < 4; ++i) {
            int r = rbase + m * 16 + (lane >> 4) * 4 + i;
            if (r >= rowsV) continue;
            size_t rowOff = (size_t)(slot0 + r) * HID + ncol0;
#pragma unroll
            for (int n = 0; n < 2; ++n) {
                int c = cbase + n * 16 + (lane & 15);
                float u = accU[m][n][i];
                float v = accV[m][n][i];
                float s = u / (1.f + __expf(-u));
                hbuf[rowOff + c] = f2bf(s * v);
            }
        }
    }
}

// ======================= GEMM2 =======================
// (Round-17/18 verbatim: 128m x 64n, counted vmcnt(6), UNPINNED grid dim3(16,32,8).)

#define G2_STAGE(AS, BS)                                                  \
    {                                                                     \
        _Pragma("unroll")                                                 \
        for (int i = 0; i < 4; ++i) { gload_lds16(aS[i], &AS[aOff[i]]); aS[i] += 64; } \
        _Pragma("unroll")                                                 \
        for (int i = 0; i < 2; ++i) { gload_lds16(bS[i], &BS[bOff[i]]); bS[i] += 64; } \
    }

#define G2_COMPUTE(AS, BS)                                                \
    {                                                                     \
        _Pragma("unroll")                                                 \
        for (int kk = 0; kk < 2; ++kk) {                                  \
            const int g = kk * 4 + lchunk;                                \
            bf16x8 af[4], bf[2];                                          \
            _Pragma("unroll")                                             \
            for (int m = 0; m < 4; ++m) {                                 \
                int r = rbase + m * 16 + lrow;                            \
                af[m] = ldsFrag(&AS[r * 64 + ((g ^ (r & 7)) * 8)]);       \
            }                                                             \
            _Pragma("unroll")                                             \
            for (int n = 0; n < 2; ++n) {                                 \
                int rn = cbase + n * 16 + lrow;                           \
                bf[n] = ldsFrag(&BS[rn * 64 + ((g ^ (rn & 7)) * 8)]);     \
            }                                                             \
            __builtin_amdgcn_s_setprio(1);                                \
            _Pragma("unroll")                                             \
            for (int m = 0; m < 4; ++m)                                   \
                _Pragma("unroll")                                         \
                for (int n = 0; n < 2; ++n)                               \
                    acc[m][n] = __builtin_amdgcn_mfma_f32_16x16x32_bf16(af[m], bf[n], acc[m][n], 0, 0, 0); \
            __builtin_amdgcn_s_setprio(0);                                \
        }                                                                 \
    }

__global__ __launch_bounds__(256, 2) void gemm2_kernel(
    const unsigned short* __restrict__ WdT, const unsigned short* __restrict__ hbuf,
    const int* __restrict__ toks, const int* __restrict__ counts, const int* __restrict__ offs,
    const float* __restrict__ gate_p, float* __restrict__ yout) {
    const int e  = blockIdx.z;
    const int mt = blockIdx.y;
    const int nt = blockIdx.x;      // 0..15
    const int Ne = counts[e];
    if (mt * 128 >= Ne) return;
    const int slot0 = offs[e] + mt * 128;
    const int rowsV = min(128, Ne - mt * 128);
    const int ncol0 = nt * 64;

    __shared__ unsigned short As0[128 * 64];
    __shared__ unsigned short As1[128 * 64];
    __shared__ unsigned short Bs0[64 * 64];
    __shared__ unsigned short Bs1[64 * 64];

    const int tid = threadIdx.x;

    const unsigned short* aS[4];
    int aOff[4];
#pragma unroll
    for (int i = 0; i < 4; ++i) {
        int c = i * 256 + tid;
        int r = c >> 3, ch = c & 7;
        int srcOff = (ch ^ (r & 7)) * 8;
        int ar = min(r, rowsV - 1);
        aS[i] = hbuf + (size_t)(slot0 + ar) * HID + srcOff;
        aOff[i] = c * 8;
    }
    const unsigned short* bS[2];
    int bOff[2];
#pragma unroll
    for (int i = 0; i < 2; ++i) {
        int c = i * 256 + tid;
        int r = c >> 3, ch = c & 7;
        int srcOff = (ch ^ (r & 7)) * 8;
        bS[i] = WdT + ((size_t)e * D_MODEL + ncol0 + r) * HID + srcOff;
        bOff[i] = c * 8;
    }

    f32x4 acc[4][2];
#pragma unroll
    for (int m = 0; m < 4; ++m)
#pragma unroll
        for (int n = 0; n < 2; ++n) acc[m][n] = (f32x4){0.f, 0.f, 0.f, 0.f};

    const int lane = tid & 63;
    const int w = tid >> 6;
    const int rbase = (w >> 1) * 64;
    const int cbase = (w & 1) * 32;
    const int lrow = lane & 15;
    const int lchunk = lane >> 4;

    // prologue: k=0 -> buf0
    G2_STAGE(As0, Bs0);

#pragma unroll 1
    for (int k2 = 0; k2 < 21; ++k2) {
        G2_STAGE(As1, Bs1);                      // k = 2k2+1
        VM_WAIT6; SBAR; SCHED0;
        G2_COMPUTE(As0, Bs0);                    // k = 2k2
        SCHED0; LGKM0; SBAR;
        G2_STAGE(As0, Bs0);                      // k = 2k2+2 (<= 42)
        VM_WAIT6; SBAR; SCHED0;
        G2_COMPUTE(As1, Bs1);                    // k = 2k2+1
        SCHED0; LGKM0; SBAR;
    }
    VM_WAIT0; SBAR; SCHED0;
    G2_COMPUTE(As0, Bs0);                        // k = 42

#pragma unroll
    for (int m = 0; m < 4; ++m) {
#pragma unroll
        for (int i = 0; i < 4; ++i) {
            int r = rbase + m * 16 + (lane >> 4) * 4 + i;
            if (r >= rowsV) continue;
            int tok = toks[slot0 + r];
            float p = gate_p[tok];
            float* yrow = yout + (size_t)tok * D_MODEL + ncol0;
#pragma unroll
            for (int n = 0; n < 2; ++n) {
                int c = cbase + n * 16 + (lane & 15);
                yrow[c] = p * acc[m][n][i];
            }
        }
    }
}

// ---------------- launch ----------------
extern "C" void kernel_launch(void* const* d_in, const int* in_sizes, int n_in,
                              void* d_out, int out_size, void* d_ws, size_t ws_size,
                              hipStream_t stream) {
    const float* x  = (const float*)d_in[0];
    const float* Wg = (const float*)d_in[1];
    const float* bg = (const float*)d_in[2];
    const float* Wu = (const float*)d_in[3];
    const float* Wv = (const float*)d_in[4];
    const float* Wd = (const float*)d_in[5];
    float* yout = (float*)d_out;
    float* aux_out = yout + (size_t)NTOK * D_MODEL;

    char* ws = (char*)d_ws;
    int*   counts = (int*)(ws + 0);
    int*   offs   = (int*)(ws + 32);
    float* ce_sum = (float*)(ws + 64);
    int*   fill   = (int*)(ws + 96);
    int*   eidx   = (int*)(ws + 128);
    float* gate_p = (float*)(ws + 16512);
    int*   toks   = (int*)(ws + 32896);
    unsigned short* xbf  = (unsigned short*)(ws + 65536);      // 8 MB
    unsigned short* hbuf = (unsigned short*)(ws + 8454144);    // 22.5 MB
    unsigned short* WuT  = (unsigned short*)(ws + 30998528);   // 43 MB
    unsigned short* WvT  = (unsigned short*)(ws + 76087296);   // 43 MB
    const size_t WDT_OFF = 121176064;
    const size_t WDT_SZ  = (size_t)NEXP * D_MODEL * HID * 2;   // 43 MB
    const bool sepWdT = ws_size >= WDT_OFF + WDT_SZ;           // proven true (round 7)
    unsigned short* WdT = sepWdT ? (unsigned short*)(ws + WDT_OFF) : WuT;

    const int nPairs = (sepWdT ? (TILES_UV + TILES_WD) : TILES_UV) / 2;

    (void)hipMemsetAsync(ws, 0, 128, stream);
    prep_kernel<<<nPairs + RTR_BLKS, 256, 0, stream>>>(
        x, Wg, bg, Wu, Wv, Wd, WuT, WvT, WdT,
        eidx, gate_p, counts, ce_sum, xbf, nPairs);
    scatter_kernel<<<16, 256, 0, stream>>>(eidx, counts, ce_sum, offs, aux_out, fill, toks);
    gemm1_kernel<<<dim3(43, 32, 8), 256, 0, stream>>>(WuT, WvT, xbf, toks, counts, offs, hbuf);
    if (!sepWdT)
        transpose_kernel<<<dim3(D_MODEL / 64, HID / 64, 8), 256, 0, stream>>>(Wd, WdT, HID, D_MODEL);
    gemm2_kernel<<<dim3(16, 32, 8), 256, 0, stream>>>(WdT, hbuf, toks, counts, offs, gate_p, yout);
}

// Round 20
// 243.999 us; speedup vs baseline: 1.0198x; 1.0198x over previous
//
#include <hip/hip_runtime.h>

// ---------------- problem constants ----------------
#define D_MODEL 1024
#define HID     2752
#define NEXP    8
#define NTOK    4096
#define ALPHA   0.05f

// prep kernel tile counts
#define TILES_PER_MAT 344          // UV: 8 d-tiles x 43 h-tiles ; WD: 43 h-tiles x 8 d-tiles
#define TILES_UV  (TILES_PER_MAT * 16)   // 5504
#define TILES_WD  (TILES_PER_MAT * 8)    // 2752
#define RTR_BLKS  1024

// LDS tile strides (u16 elements, odd-word to spread banks)
#define TSU 66    // UV tile [128][66]
#define TSW 130   // WD tile [64][130]

typedef __bf16 bf16_t;
typedef bf16_t bf16x8 __attribute__((ext_vector_type(8)));
typedef float  f32x4  __attribute__((ext_vector_type(4)));
typedef float  vf4    __attribute__((ext_vector_type(4)));

// counted-wait primitives (T3/T4)
#define VM_WAIT8  asm volatile("s_waitcnt vmcnt(8)" ::: "memory")
#define VM_WAIT6  asm volatile("s_waitcnt vmcnt(6)" ::: "memory")
#define VM_WAIT0  asm volatile("s_waitcnt vmcnt(0)" ::: "memory")
#define LGKM0     asm volatile("s_waitcnt lgkmcnt(0)" ::: "memory")
#define SBAR      __builtin_amdgcn_s_barrier()
#define SCHED0    __builtin_amdgcn_sched_barrier(0)

__device__ inline unsigned short f2bf(float f) {
    unsigned int u = __float_as_uint(f);
    u += 0x7fffu + ((u >> 16) & 1u);   // round-to-nearest-even
    return (unsigned short)(u >> 16);
}

__device__ inline bf16x8 ldsFrag(const unsigned short* p) {
    union { uint4 u; bf16x8 b; } t;
    t.u = *(const uint4*)p;
    return t.b;
}

__device__ inline void gload_lds16(const void* g, void* l) {
    __builtin_amdgcn_global_load_lds((const __attribute__((address_space(1))) void*)g,
                                     (__attribute__((address_space(3))) void*)l, 16, 0, 0);
}

// ---------------- prep: weight transposes + router, one dispatch ----------------
// Round-18 proven body (2-tile pipeline, NT loads).
struct TileP {
    const float* src;
    unsigned short* dst;
    int r0, c0;
    bool uv;
};

__device__ inline TileP tileParams(int tt, const float* Wu, const float* Wv, const float* Wd,
                                   unsigned short* WuT, unsigned short* WvT, unsigned short* WdT) {
    TileP p;
    const int z  = tt / TILES_PER_MAT;
    const int rm = tt - z * TILES_PER_MAT;
    const int bx = rm % 43;
    const int by = rm / 43;
    if (z < 16) {
        const int e = z & 7;
        p.src = ((z < 8) ? Wu : Wv) + (size_t)e * D_MODEL * HID;
        p.dst = ((z < 8) ? WuT : WvT) + (size_t)e * D_MODEL * HID;
        p.r0 = by * 128; p.c0 = bx * 64; p.uv = true;
    } else {
        const int e = z - 16;
        p.src = Wd + (size_t)e * HID * D_MODEL;
        p.dst = WdT + (size_t)e * HID * D_MODEL;
        p.r0 = bx * 64; p.c0 = by * 128; p.uv = false;
    }
    return p;
}

__device__ inline void issueLoads(const TileP& p, int tid, vf4* v) {
    if (p.uv) {
#pragma unroll
        for (int j = 0; j < 8; ++j) {
            int f = j * 256 + tid;
            int row = f >> 4, c4 = (f & 15) * 4;
            v[j] = __builtin_nontemporal_load(
                (const vf4*)(p.src + (size_t)(p.r0 + row) * HID + p.c0 + c4));
        }
    } else {
#pragma unroll
        for (int j = 0; j < 8; ++j) {
            int f = j * 256 + tid;
            int row = f >> 5, c4 = (f & 31) * 4;
            v[j] = __builtin_nontemporal_load(
                (const vf4*)(p.src + (size_t)(p.r0 + row) * D_MODEL + p.c0 + c4));
        }
    }
}

__device__ inline void convertWrite(const TileP& p, int tid, const vf4* v, unsigned short* tile) {
    if (p.uv) {
#pragma unroll
        for (int j = 0; j < 8; ++j) {
            int f = j * 256 + tid;
            int row = f >> 4, c4 = (f & 15) * 4;
            unsigned int p0 = (unsigned)f2bf(v[j].x) | ((unsigned)f2bf(v[j].y) << 16);
            unsigned int p1 = (unsigned)f2bf(v[j].z) | ((unsigned)f2bf(v[j].w) << 16);
            unsigned int* tp = (unsigned int*)&tile[row * TSU + c4];
            tp[0] = p0; tp[1] = p1;
        }
    } else {
#pragma unroll
        for (int j = 0; j < 8; ++j) {
            int f = j * 256 + tid;
            int row = f >> 5, c4 = (f & 31) * 4;
            unsigned int p0 = (unsigned)f2bf(v[j].x) | ((unsigned)f2bf(v[j].y) << 16);
            unsigned int p1 = (unsigned)f2bf(v[j].z) | ((unsigned)f2bf(v[j].w) << 16);
            unsigned int* tp = (unsigned int*)&tile[row * TSW + c4];
            tp[0] = p0; tp[1] = p1;
        }
    }
}

__device__ inline void phase2(const TileP& p, int tid, const unsigned short* tile) {
    if (p.uv) {
#pragma unroll
        for (int j = 0; j < 4; ++j) {
            int f = j * 256 + tid;
            int oc = f >> 4, kc = f & 15;
            unsigned int w[4];
#pragma unroll
            for (int q = 0; q < 4; ++q) {
                unsigned int lo = tile[(kc * 8 + 2 * q)     * TSU + oc];
                unsigned int hi = tile[(kc * 8 + 2 * q + 1) * TSU + oc];
                w[q] = lo | (hi << 16);
            }
            uint4 out; out.x = w[0]; out.y = w[1]; out.z = w[2]; out.w = w[3];
            *(uint4*)(p.dst + (size_t)(p.c0 + oc) * D_MODEL + p.r0 + kc * 8) = out;
        }
    } else {
#pragma unroll
        for (int j = 0; j < 4; ++j) {
            int f = j * 256 + tid;
            int oc = f >> 3, kc = f & 7;
            unsigned int w[4];
#pragma unroll
            for (int q = 0; q < 4; ++q) {
                unsigned int lo = tile[(kc * 8 + 2 * q)     * TSW + oc];
                unsigned int hi = tile[(kc * 8 + 2 * q + 1) * TSW + oc];
                w[q] = lo | (hi << 16);
            }
            uint4 out; out.x = w[0]; out.y = w[1]; out.z = w[2]; out.w = w[3];
            *(uint4*)(p.dst + (size_t)(p.c0 + oc) * HID + p.r0 + kc * 8) = out;
        }
    }
}

__global__ __launch_bounds__(256) void prep_kernel(
    const float* __restrict__ x, const float* __restrict__ Wg, const float* __restrict__ bg,
    const float* __restrict__ Wu, const float* __restrict__ Wv, const float* __restrict__ Wd,
    unsigned short* __restrict__ WuT, unsigned short* __restrict__ WvT,
    unsigned short* __restrict__ WdT,
    int* __restrict__ eidx, float* __restrict__ gate_p,
    int* __restrict__ counts, float* __restrict__ ce_sum,
    unsigned short* __restrict__ xbf, int nPairs) {

    __shared__ __align__(16) unsigned short tile[128 * TSU];   // 16896 B (>= 64*TSW)
    const int id = blockIdx.x;
    const int tid = threadIdx.x;

    if (id < nPairs) {
        TileP p0 = tileParams(2 * id,     Wu, Wv, Wd, WuT, WvT, WdT);
        TileP p1 = tileParams(2 * id + 1, Wu, Wv, Wd, WuT, WvT, WdT);
        vf4 v[8];

        issueLoads(p0, tid, v);
        convertWrite(p0, tid, v, tile);
        __syncthreads();
        issueLoads(p1, tid, v);            // T1 loads fly under T0 phase-2
        SCHED0;
        phase2(p0, tid, tile);
        __syncthreads();
        convertWrite(p1, tid, v, tile);
        __syncthreads();
        phase2(p1, tid, tile);
        return;
    }

    // ---- router role ----
    float* ceS = (float*)tile;
    int*   cntS = (int*)tile + 8;
    if (tid < 8) { ceS[tid] = 0.f; cntS[tid] = 0; }
    __syncthreads();

    const int rid = id - nPairs;
    const int wid = tid >> 6, lane = tid & 63;
    const int t = rid * 4 + wid;
    const float* xr = x + (size_t)t * D_MODEL;
    unsigned short* xbr = xbf + (size_t)t * D_MODEL;

    float acc[8];
#pragma unroll
    for (int e = 0; e < 8; ++e) acc[e] = 0.f;

#pragma unroll
    for (int c = 0; c < 4; ++c) {
        int i0 = c * 256 + lane * 4;
        float4 xv = *(const float4*)(xr + i0);
        uint2 pk;
        pk.x = (unsigned)f2bf(xv.x) | ((unsigned)f2bf(xv.y) << 16);
        pk.y = (unsigned)f2bf(xv.z) | ((unsigned)f2bf(xv.w) << 16);
        *(uint2*)(xbr + i0) = pk;
#pragma unroll
        for (int j = 0; j < 4; ++j) {
            const float* wr = Wg + (size_t)(i0 + j) * 8;
            float4 lo = *(const float4*)(wr);
            float4 hi = *(const float4*)(wr + 4);
            float xs = (&xv.x)[j];
            acc[0] += xs * lo.x; acc[1] += xs * lo.y;
            acc[2] += xs * lo.z; acc[3] += xs * lo.w;
            acc[4] += xs * hi.x; acc[5] += xs * hi.y;
            acc[6] += xs * hi.z; acc[7] += xs * hi.w;
        }
    }
#pragma unroll
    for (int e = 0; e < 8; ++e) {
#pragma unroll
        for (int off = 32; off > 0; off >>= 1)
            acc[e] += __shfl_xor(acc[e], off, 64);
    }

    if (lane == 0) {
        float lg[8];
#pragma unroll
        for (int e = 0; e < 8; ++e) lg[e] = acc[e] + bg[e];
        float mx = lg[0]; int am = 0;
#pragma unroll
        for (int e = 1; e < 8; ++e) { if (lg[e] > mx) { mx = lg[e]; am = e; } }
        float ex[8], s = 0.f;
#pragma unroll
        for (int e = 0; e < 8; ++e) { ex[e] = __expf(lg[e] - mx); s += ex[e]; }
        float inv = 1.f / s;
#pragma unroll
        for (int e = 0; e < 8; ++e) atomicAdd(&ceS[e], ex[e] * inv);
        atomicAdd(&cntS[am], 1);
        eidx[t] = am;
        gate_p[t] = ex[am] * inv;
    }
    __syncthreads();
    if (tid < 8) atomicAdd(&ce_sum[tid], ceS[tid]);
    if (tid >= 8 && tid < 16) atomicAdd(&counts[tid - 8], cntS[tid - 8]);
}

// standalone Wd transpose (fallback when WdT must alias WuT; runs after gemm1)
__global__ __launch_bounds__(256) void transpose_kernel(const float* __restrict__ in,
                                                        unsigned short* __restrict__ out,
                                                        int R, int C) {
    __shared__ float tile[64 * 65];
    const int e = blockIdx.z;
    const float* src = in + (size_t)e * R * C;
    unsigned short* dst = out + (size_t)e * R * C;
    const int c0 = blockIdx.x * 64, r0 = blockIdx.y * 64;
    const int tid = threadIdx.x;
#pragma unroll
    for (int j = 0; j < 4; ++j) {
        int f = j * 256 + tid;
        int row = f >> 4, c4 = f & 15;
        float4 v = *(const float4*)(src + (size_t)(r0 + row) * C + c0 + c4 * 4);
        float* t = &tile[row * 65 + c4 * 4];
        t[0] = v.x; t[1] = v.y; t[2] = v.z; t[3] = v.w;
    }
    __syncthreads();
#pragma unroll
    for (int j = 0; j < 2; ++j) {
        int f = j * 256 + tid;
        int orow = f >> 3, kc = f & 7;
        unsigned short pk[8];
#pragma unroll
        for (int q = 0; q < 8; ++q) pk[q] = f2bf(tile[(kc * 8 + q) * 65 + orow]);
        *(uint4*)(dst + (size_t)(c0 + orow) * R + r0 + kc * 8) = *(uint4*)pk;
    }
}

// ---------------- scatter (+ folded offsets/aux) ----------------
__global__ void scatter_kernel(const int* __restrict__ eidx, const int* __restrict__ counts,
                               const float* __restrict__ ce_sum,
                               int* __restrict__ offs, float* __restrict__ aux_out,
                               int* __restrict__ fill, int* __restrict__ toks) {
    __shared__ int offS[8];
    const int tid = threadIdx.x;
    if (tid == 0) {
        int off = 0; float aux = 0.f;
#pragma unroll
        for (int e = 0; e < 8; ++e) {
            offS[e] = off;
            if (blockIdx.x == 0) offs[e] = off;
            off += counts[e];
            aux += ((float)counts[e] / (float)NTOK) * (ce_sum[e] / (float)NTOK);
        }
        if (blockIdx.x == 0) aux_out[0] = ALPHA * (float)NEXP * aux;
    }
    __syncthreads();
    int t = blockIdx.x * 256 + tid;
    int e = eidx[t];
    int pos = atomicAdd(&fill[e], 1);
    toks[offS[e] + pos] = t;
}

// ======================= GEMM1 =======================
// Round-13/18 proven: 128m x 64n, BK=64, 4 waves, static ping-pong dbuf,
// counted vmcnt(8). (BK=32 variant regressed in round 19 — reverted.)

#define G1_STAGE(AS, BUS, BVS)                                            \
    {                                                                     \
        _Pragma("unroll")                                                 \
        for (int i = 0; i < 2; ++i) { gload_lds16(aS[i], &AS[aOff[i]]); aS[i] += 64; } \
        gload_lds16(aS[2], &AS[aOff[2]]); aS[2] += 64;                    \
        gload_lds16(aS[3], &AS[aOff[3]]); aS[3] += 64;                    \
        _Pragma("unroll")                                                 \
        for (int i = 0; i < 2; ++i) {                                     \
            gload_lds16(buS[i], &BUS[bOff[i]]); buS[i] += 64;             \
            gload_lds16(bvS[i], &BVS[bOff[i]]); bvS[i] += 64;             \
        }                                                                 \
    }

#define G1_COMPUTE(AS, BUS, BVS)                                          \
    {                                                                     \
        _Pragma("unroll")                                                 \
        for (int kk = 0; kk < 2; ++kk) {                                  \
            const int g = kk * 4 + lchunk;                                \
            bf16x8 af[4], bu[2], bv[2];                                   \
            _Pragma("unroll")                                             \
            for (int m = 0; m < 4; ++m) {                                 \
                int r = rbase + m * 16 + lrow;                            \
                af[m] = ldsFrag(&AS[r * 64 + ((g ^ (r & 7)) * 8)]);       \
            }                                                             \
            _Pragma("unroll")                                             \
            for (int n = 0; n < 2; ++n) {                                 \
                int rn = cbase + n * 16 + lrow;                           \
                int off = rn * 64 + ((g ^ (rn & 7)) * 8);                 \
                bu[n] = ldsFrag(&BUS[off]);                               \
                bv[n] = ldsFrag(&BVS[off]);                               \
            }                                                             \
            __builtin_amdgcn_s_setprio(1);                                \
            _Pragma("unroll")                                             \
            for (int m = 0; m < 4; ++m)                                   \
                _Pragma("unroll")                                         \
                for (int n = 0; n < 2; ++n) {                             \
                    accU[m][n] = __builtin_amdgcn_mfma_f32_16x16x32_bf16(af[m], bu[n], accU[m][n], 0, 0, 0); \
                    accV[m][n] = __builtin_amdgcn_mfma_f32_16x16x32_bf16(af[m], bv[n], accV[m][n], 0, 0, 0); \
                }                                                         \
            __builtin_amdgcn_s_setprio(0);                                \
        }                                                                 \
    }

__global__ __launch_bounds__(256, 2) void gemm1_kernel(
    const unsigned short* __restrict__ WuT, const unsigned short* __restrict__ WvT,
    const unsigned short* __restrict__ xbf,
    const int* __restrict__ toks, const int* __restrict__ counts, const int* __restrict__ offs,
    unsigned short* __restrict__ hbuf) {
    const int e  = blockIdx.z;
    const int mt = blockIdx.y;
    const int nt = blockIdx.x;           // 0..42
    const int Ne = counts[e];
    if (mt * 128 >= Ne) return;
    const int slot0 = offs[e] + mt * 128;
    const int rowsV = min(128, Ne - mt * 128);
    const int ncol0 = nt * 64;

    __shared__ unsigned short As0[128 * 64];
    __shared__ unsigned short As1[128 * 64];
    __shared__ unsigned short Bus0[64 * 64];
    __shared__ unsigned short Bus1[64 * 64];
    __shared__ unsigned short Bvs0[64 * 64];
    __shared__ unsigned short Bvs1[64 * 64];

    const int tid = threadIdx.x;

    const unsigned short* aS[4];
    int aOff[4];
#pragma unroll
    for (int i = 0; i < 4; ++i) {
        int c = i * 256 + tid;
        int r = c >> 3, ch = c & 7;
        int srcOff = (ch ^ (r & 7)) * 8;
        int ar = min(r, rowsV - 1);
        int tok = toks[slot0 + ar];
        aS[i] = xbf + (size_t)tok * D_MODEL + srcOff;
        aOff[i] = c * 8;
    }
    const unsigned short *buS[2], *bvS[2];
    int bOff[2];
#pragma unroll
    for (int i = 0; i < 2; ++i) {
        int c = i * 256 + tid;
        int r = c >> 3, ch = c & 7;
        int srcOff = (ch ^ (r & 7)) * 8;
        int bn = ncol0 + r;
        buS[i] = WuT + ((size_t)e * HID + bn) * D_MODEL + srcOff;
        bvS[i] = WvT + ((size_t)e * HID + bn) * D_MODEL + srcOff;
        bOff[i] = c * 8;
    }

    f32x4 accU[4][2], accV[4][2];
#pragma unroll
    for (int m = 0; m < 4; ++m)
#pragma unroll
        for (int n = 0; n < 2; ++n) {
            accU[m][n] = (f32x4){0.f, 0.f, 0.f, 0.f};
            accV[m][n] = (f32x4){0.f, 0.f, 0.f, 0.f};
        }

    const int lane = tid & 63;
    const int w = tid >> 6;
    const int rbase = (w >> 1) * 64;
    const int cbase = (w & 1) * 32;
    const int lrow = lane & 15;
    const int lchunk = lane >> 4;

    // prologue: k=0 -> buf0 (8 VMEM outstanding)
    G1_STAGE(As0, Bus0, Bvs0);

#pragma unroll 1
    for (int k2 = 0; k2 < 7; ++k2) {
        G1_STAGE(As1, Bus1, Bvs1);               // k = 2k2+1
        VM_WAIT8; SBAR; SCHED0;
        G1_COMPUTE(As0, Bus0, Bvs0);             // k = 2k2
        SCHED0; LGKM0; SBAR;
        G1_STAGE(As0, Bus0, Bvs0);               // k = 2k2+2
        VM_WAIT8; SBAR; SCHED0;
        G1_COMPUTE(As1, Bus1, Bvs1);             // k = 2k2+1
        SCHED0; LGKM0; SBAR;
    }
    G1_STAGE(As1, Bus1, Bvs1);                   // k = 15
    VM_WAIT8; SBAR; SCHED0;
    G1_COMPUTE(As0, Bus0, Bvs0);                 // k = 14
    SCHED0; LGKM0; SBAR;
    VM_WAIT0; SBAR; SCHED0;
    G1_COMPUTE(As1, Bus1, Bvs1);                 // k = 15

    // epilogue: h = silu(u) * v (bf16); HID = 43*64 so no column guard
#pragma unroll
    for (int m = 0; m < 4; ++m) {
#pragma unroll
        for (int i = 0; i < 4; ++i) {
            int r = rbase + m * 16 + (lane >> 4) * 4 + i;
            if (r >= rowsV) continue;
            size_t rowOff = (size_t)(slot0 + r) * HID + ncol0;
#pragma unroll
            for (int n = 0; n < 2; ++n) {
                int c = cbase + n * 16 + (lane & 15);
                float u = accU[m][n][i];
                float v = accV[m][n][i];
                float s = u / (1.f + __expf(-u));
                hbuf[rowOff + c] = f2bf(s * v);
            }
        }
    }
}

// ======================= GEMM2 =======================
// (Round-17/18 verbatim: 128m x 64n, counted vmcnt(6), UNPINNED grid dim3(16,32,8).)

#define G2_STAGE(AS, BS)                                                  \
    {                                                                     \
        _Pragma("unroll")                                                 \
        for (int i = 0; i < 4; ++i) { gload_lds16(aS[i], &AS[aOff[i]]); aS[i] += 64; } \
        _Pragma("unroll")                                                 \
        for (int i = 0; i < 2; ++i) { gload_lds16(bS[i], &BS[bOff[i]]); bS[i] += 64; } \
    }

#define G2_COMPUTE(AS, BS)                                                \
    {                                                                     \
        _Pragma("unroll")                                                 \
        for (int kk = 0; kk < 2; ++kk) {                                  \
            const int g = kk * 4 + lchunk;                                \
            bf16x8 af[4], bf[2];                                          \
            _Pragma("unroll")                                             \
            for (int m = 0; m < 4; ++m) {                                 \
                int r = rbase + m * 16 + lrow;                            \
                af[m] = ldsFrag(&AS[r * 64 + ((g ^ (r & 7)) * 8)]);       \
            }                                                             \
            _Pragma("unroll")                                             \
            for (int n = 0; n < 2; ++n) {                                 \
                int rn = cbase + n * 16 + lrow;                           \
                bf[n] = ldsFrag(&BS[rn * 64 + ((g ^ (rn & 7)) * 8)]);     \
            }                                                             \
            __builtin_amdgcn_s_setprio(1);                                \
            _Pragma("unroll")                                             \
            for (int m = 0; m < 4; ++m)                                   \
                _Pragma("unroll")                                         \
                for (int n = 0; n < 2; ++n)                               \
                    acc[m][n] = __builtin_amdgcn_mfma_f32_16x16x32_bf16(af[m], bf[n], acc[m][n], 0, 0, 0); \
            __builtin_amdgcn_s_setprio(0);                                \
        }                                                                 \
    }

__global__ __launch_bounds__(256, 2) void gemm2_kernel(
    const unsigned short* __restrict__ WdT, const unsigned short* __restrict__ hbuf,
    const int* __restrict__ toks, const int* __restrict__ counts, const int* __restrict__ offs,
    const float* __restrict__ gate_p, float* __restrict__ yout) {
    const int e  = blockIdx.z;
    const int mt = blockIdx.y;
    const int nt = blockIdx.x;      // 0..15
    const int Ne = counts[e];
    if (mt * 128 >= Ne) return;
    const int slot0 = offs[e] + mt * 128;
    const int rowsV = min(128, Ne - mt * 128);
    const int ncol0 = nt * 64;

    __shared__ unsigned short As0[128 * 64];
    __shared__ unsigned short As1[128 * 64];
    __shared__ unsigned short Bs0[64 * 64];
    __shared__ unsigned short Bs1[64 * 64];

    const int tid = threadIdx.x;

    const unsigned short* aS[4];
    int aOff[4];
#pragma unroll
    for (int i = 0; i < 4; ++i) {
        int c = i * 256 + tid;
        int r = c >> 3, ch = c & 7;
        int srcOff = (ch ^ (r & 7)) * 8;
        int ar = min(r, rowsV - 1);
        aS[i] = hbuf + (size_t)(slot0 + ar) * HID + srcOff;
        aOff[i] = c * 8;
    }
    const unsigned short* bS[2];
    int bOff[2];
#pragma unroll
    for (int i = 0; i < 2; ++i) {
        int c = i * 256 + tid;
        int r = c >> 3, ch = c & 7;
        int srcOff = (ch ^ (r & 7)) * 8;
        bS[i] = WdT + ((size_t)e * D_MODEL + ncol0 + r) * HID + srcOff;
        bOff[i] = c * 8;
    }

    f32x4 acc[4][2];
#pragma unroll
    for (int m = 0; m < 4; ++m)
#pragma unroll
        for (int n = 0; n < 2; ++n) acc[m][n] = (f32x4){0.f, 0.f, 0.f, 0.f};

    const int lane = tid & 63;
    const int w = tid >> 6;
    const int rbase = (w >> 1) * 64;
    const int cbase = (w & 1) * 32;
    const int lrow = lane & 15;
    const int lchunk = lane >> 4;

    // prologue: k=0 -> buf0
    G2_STAGE(As0, Bs0);

#pragma unroll 1
    for (int k2 = 0; k2 < 21; ++k2) {
        G2_STAGE(As1, Bs1);                      // k = 2k2+1
        VM_WAIT6; SBAR; SCHED0;
        G2_COMPUTE(As0, Bs0);                    // k = 2k2
        SCHED0; LGKM0; SBAR;
        G2_STAGE(As0, Bs0);                      // k = 2k2+2 (<= 42)
        VM_WAIT6; SBAR; SCHED0;
        G2_COMPUTE(As1, Bs1);                    // k = 2k2+1
        SCHED0; LGKM0; SBAR;
    }
    VM_WAIT0; SBAR; SCHED0;
    G2_COMPUTE(As0, Bs0);                        // k = 42

#pragma unroll
    for (int m = 0; m < 4; ++m) {
#pragma unroll
        for (int i = 0; i < 4; ++i) {
            int r = rbase + m * 16 + (lane >> 4) * 4 + i;
            if (r >= rowsV) continue;
            int tok = toks[slot0 + r];
            float p = gate_p[tok];
            float* yrow = yout + (size_t)tok * D_MODEL + ncol0;
#pragma unroll
            for (int n = 0; n < 2; ++n) {
                int c = cbase + n * 16 + (lane & 15);
                yrow[c] = p * acc[m][n][i];
            }
        }
    }
}

// ---------------- launch ----------------
extern "C" void kernel_launch(void* const* d_in, const int* in_sizes, int n_in,
                              void* d_out, int out_size, void* d_ws, size_t ws_size,
                              hipStream_t stream) {
    const float* x  = (const float*)d_in[0];
    const float* Wg = (const float*)d_in[1];
    const float* bg = (const float*)d_in[2];
    const float* Wu = (const float*)d_in[3];
    const float* Wv = (const float*)d_in[4];
    const float* Wd = (const float*)d_in[5];
    float* yout = (float*)d_out;
    float* aux_out = yout + (size_t)NTOK * D_MODEL;

    char* ws = (char*)d_ws;
    int*   counts = (int*)(ws + 0);
    int*   offs   = (int*)(ws + 32);
    float* ce_sum = (float*)(ws + 64);
    int*   fill   = (int*)(ws + 96);
    int*   eidx   = (int*)(ws + 128);
    float* gate_p = (float*)(ws + 16512);
    int*   toks   = (int*)(ws + 32896);
    unsigned short* xbf  = (unsigned short*)(ws + 65536);      // 8 MB
    unsigned short* hbuf = (unsigned short*)(ws + 8454144);    // 22.5 MB
    unsigned short* WuT  = (unsigned short*)(ws + 30998528);   // 43 MB
    unsigned short* WvT  = (unsigned short*)(ws + 76087296);   // 43 MB
    const size_t WDT_OFF = 121176064;
    const size_t WDT_SZ  = (size_t)NEXP * D_MODEL * HID * 2;   // 43 MB
    const bool sepWdT = ws_size >= WDT_OFF + WDT_SZ;           // proven true (round 7)
    unsigned short* WdT = sepWdT ? (unsigned short*)(ws + WDT_OFF) : WuT;

    const int nPairs = (sepWdT ? (TILES_UV + TILES_WD) : TILES_UV) / 2;

    (void)hipMemsetAsync(ws, 0, 128, stream);
    prep_kernel<<<nPairs + RTR_BLKS, 256, 0, stream>>>(
        x, Wg, bg, Wu, Wv, Wd, WuT, WvT, WdT,
        eidx, gate_p, counts, ce_sum, xbf, nPairs);
    scatter_kernel<<<16, 256, 0, stream>>>(eidx, counts, ce_sum, offs, aux_out, fill, toks);
    gemm1_kernel<<<dim3(43, 32, 8), 256, 0, stream>>>(WuT, WvT, xbf, toks, counts, offs, hbuf);
    if (!sepWdT)
        transpose_kernel<<<dim3(D_MODEL / 64, HID / 64, 8), 256, 0, stream>>>(Wd, WdT, HID, D_MODEL);
    gemm2_kernel<<<dim3(16, 32, 8), 256, 0, stream>>>(WdT, hbuf, toks, counts, offs, gate_p, yout);
}